// Round 1
// baseline (505.884 us; speedup 1.0000x reference)
//
#include <hip/hip_runtime.h>
#include <math.h>

// CIF kernel. Key algebra: tokens[b,n,:] = (sum_t w[b,t,n] * h[b,t,:]) @ Wv + cif_mass[b,n]*bv
// so we never materialize v = h@Wv (34 GFLOP) nor dense w (26 TFLOP einsum).
// w is band-sparse: c = cumsum(alpha) is monotone -> each bin n covers a contiguous
// frame range found by binary search on c.

#define T_LEN 4096
#define D_DIM 512
#define HID   128
#define N_MAX 400
#define B_SZ  16
#define EPSF  1e-8f

#define FMA16(W, X0, X1, X2, X3) do { \
  acc[0][0] += (X0)*(W).x; acc[0][1] += (X0)*(W).y; acc[0][2] += (X0)*(W).z; acc[0][3] += (X0)*(W).w; \
  acc[1][0] += (X1)*(W).x; acc[1][1] += (X1)*(W).y; acc[1][2] += (X1)*(W).z; acc[1][3] += (X1)*(W).w; \
  acc[2][0] += (X2)*(W).x; acc[2][1] += (X2)*(W).y; acc[2][2] += (X2)*(W).z; acc[2][3] += (X2)*(W).w; \
  acc[3][0] += (X3)*(W).x; acc[3][1] += (X3)*(W).y; acc[3][2] += (X3)*(W).z; acc[3][3] += (X3)*(W).w; \
} while (0)

// ---------------------------------------------------------------------------
// K1: raw_alpha = softplus(silu(LN(h) @ W1 + b1) @ W2 + b2)   [B*T rows]
// 32 rows per block, 256 threads. LN'd rows staged in LDS (stride 516: 16B-
// aligned float4 + bank-conflict-free for the 2-address broadcast pattern).
// Phase B: thread = (rg 0..7 -> 4 rows) x (jl 0..31 -> 4 hidden cols), k-step 4.
// ---------------------------------------------------------------------------
__global__ __launch_bounds__(256) void alpha_net_kernel(
    const float* __restrict__ h,
    const float* __restrict__ ln_g, const float* __restrict__ ln_b,
    const float* __restrict__ W1,   const float* __restrict__ b1,
    const float* __restrict__ W2,   const float* __restrict__ b2,
    float* __restrict__ raw_alpha)
{
    __shared__ float xn[32][516];
    const int tid  = threadIdx.x;
    const int row0 = blockIdx.x * 32;

    // ---- load 32 rows (32*512 f32) as float4, coalesced ----
    const float4* hsrc = (const float4*)(h + (size_t)row0 * D_DIM);
    #pragma unroll
    for (int i = 0; i < 16; ++i) {
        int idx = tid + i * 256;                 // 0..4095
        float4 v = hsrc[idx];
        *(float4*)&xn[idx >> 7][(idx & 127) << 2] = v;
    }
    __syncthreads();

    // ---- LayerNorm per row: 4 waves x 8 rows, contiguous float4 per lane ----
    const int wave = tid >> 6;
    const int lane = tid & 63;
    const int c1 = lane * 4;
    const int c2 = 256 + lane * 4;
    #pragma unroll
    for (int rr = 0; rr < 8; ++rr) {
        int r = wave * 8 + rr;
        float4 a  = *(const float4*)&xn[r][c1];
        float4 bq = *(const float4*)&xn[r][c2];
        float s  = a.x + a.y + a.z + a.w + bq.x + bq.y + bq.z + bq.w;
        float sq = a.x*a.x + a.y*a.y + a.z*a.z + a.w*a.w
                 + bq.x*bq.x + bq.y*bq.y + bq.z*bq.z + bq.w*bq.w;
        #pragma unroll
        for (int off = 32; off >= 1; off >>= 1) {
            s  += __shfl_xor(s,  off);
            sq += __shfl_xor(sq, off);
        }
        float mu  = s * (1.0f / 512.0f);
        float var = sq * (1.0f / 512.0f) - mu * mu;
        float inv = rsqrtf(var + 1e-5f);
        float4 g1 = *(const float4*)&ln_g[c1];
        float4 g2 = *(const float4*)&ln_g[c2];
        float4 o1 = *(const float4*)&ln_b[c1];
        float4 o2 = *(const float4*)&ln_b[c2];
        a.x  = (a.x  - mu) * inv * g1.x + o1.x;
        a.y  = (a.y  - mu) * inv * g1.y + o1.y;
        a.z  = (a.z  - mu) * inv * g1.z + o1.z;
        a.w  = (a.w  - mu) * inv * g1.w + o1.w;
        bq.x = (bq.x - mu) * inv * g2.x + o2.x;
        bq.y = (bq.y - mu) * inv * g2.y + o2.y;
        bq.z = (bq.z - mu) * inv * g2.z + o2.z;
        bq.w = (bq.w - mu) * inv * g2.w + o2.w;
        *(float4*)&xn[r][c1] = a;
        *(float4*)&xn[r][c2] = bq;
    }
    __syncthreads();

    // ---- xn @ W1: 4 rows x 4 cols per thread, k in steps of 4 ----
    const int jl = tid & 31;
    const int rg = tid >> 5;
    const int j4 = jl * 4;
    const int rbase = rg * 4;
    float acc[4][4] = {};
    for (int k4 = 0; k4 < 128; ++k4) {
        int k = k4 << 2;
        float4 wA = *(const float4*)&W1[(k + 0) * HID + j4];
        float4 wB = *(const float4*)&W1[(k + 1) * HID + j4];
        float4 wC = *(const float4*)&W1[(k + 2) * HID + j4];
        float4 wD = *(const float4*)&W1[(k + 3) * HID + j4];
        float4 x0 = *(const float4*)&xn[rbase + 0][k];
        float4 x1 = *(const float4*)&xn[rbase + 1][k];
        float4 x2 = *(const float4*)&xn[rbase + 2][k];
        float4 x3 = *(const float4*)&xn[rbase + 3][k];
        FMA16(wA, x0.x, x1.x, x2.x, x3.x);
        FMA16(wB, x0.y, x1.y, x2.y, x3.y);
        FMA16(wC, x0.z, x1.z, x2.z, x3.z);
        FMA16(wD, x0.w, x1.w, x2.w, x3.w);
    }

    // ---- +b1, SiLU, dot W2 over this thread's 4 cols, reduce across 32 lanes ----
    float4 b1q = *(const float4*)&b1[j4];
    float4 w2q = *(const float4*)&W2[j4];
    float b2s  = b2[0];
    float srow[4];
    #pragma unroll
    for (int r = 0; r < 4; ++r) {
        float z0 = acc[r][0] + b1q.x;
        float z1 = acc[r][1] + b1q.y;
        float z2 = acc[r][2] + b1q.z;
        float z3 = acc[r][3] + b1q.w;
        float s = z0 / (1.f + expf(-z0)) * w2q.x
                + z1 / (1.f + expf(-z1)) * w2q.y
                + z2 / (1.f + expf(-z2)) * w2q.z
                + z3 / (1.f + expf(-z3)) * w2q.w;
        s += __shfl_xor(s, 16);
        s += __shfl_xor(s, 8);
        s += __shfl_xor(s, 4);
        s += __shfl_xor(s, 2);
        s += __shfl_xor(s, 1);
        srow[r] = s;
    }
    if (jl == 0) {
        #pragma unroll
        for (int r = 0; r < 4; ++r) {
            float z  = srow[r] + b2s;
            // jax softplus = logaddexp(z, 0) = max(z,0) + log1p(exp(-|z|))
            float sp = fmaxf(z, 0.f) + log1pf(expf(-fabsf(z)));
            raw_alpha[row0 + rbase + r] = sp;
        }
    }
}

// ---------------------------------------------------------------------------
// K2: per-batch masked sum -> scale -> alpha -> inclusive cumsum c (to ws).
// One block per batch, 1024 threads, 4 sequential chunks with carry.
// ---------------------------------------------------------------------------
__global__ __launch_bounds__(1024) void scan_kernel(
    const float* __restrict__ raw, const int* __restrict__ tgt,
    const int* __restrict__ ilen, float* __restrict__ alpha_out,
    float* __restrict__ c_out)
{
    __shared__ float red[1024];
    __shared__ float sh_scale, sh_uu, sh_unif;
    const int b   = blockIdx.x;
    const int tid = threadIdx.x;
    const int L   = min(ilen[b], T_LEN);
    const float Nf = (float)tgt[b];
    const float* rb = raw + b * T_LEN;

    float local = 0.f;
    for (int t = tid; t < T_LEN; t += 1024)
        if (t < L) local += rb[t];
    red[tid] = local;
    __syncthreads();
    for (int off = 512; off >= 1; off >>= 1) {
        if (tid < off) red[tid] += red[tid + off];
        __syncthreads();
    }
    if (tid == 0) {
        float sums = red[0];
        sh_scale = Nf / (sums + EPSF);
        sh_uu    = (sums < 10.f * EPSF) ? 1.f : 0.f;
        sh_unif  = Nf / fmaxf((float)L, 1.f);
    }
    __syncthreads();
    const float scale = sh_scale, uu = sh_uu, unif = sh_unif;

    float carry = 0.f;
    for (int ch = 0; ch < 4; ++ch) {
        int t = (ch << 10) + tid;
        float m   = (t < L) ? 1.f : 0.f;
        float as_ = rb[t] * m * scale;
        float a   = as_ * (1.f - uu) + m * unif * uu;
        alpha_out[b * T_LEN + t] = a;
        __syncthreads();                  // protect red[] from previous chunk readers
        red[tid] = a;
        __syncthreads();
        for (int off = 1; off < 1024; off <<= 1) {   // Hillis-Steele inclusive scan
            float tv = (tid >= off) ? red[tid - off] : 0.f;
            __syncthreads();
            red[tid] += tv;
            __syncthreads();
        }
        c_out[b * T_LEN + t] = carry + red[tid];
        carry += red[1023];
    }
}

// ---------------------------------------------------------------------------
// K3: per (b, bin n): binary-search contiguous frame range, accumulate
// hw[b,n,:] = sum_t w*h[b,t,:], plus cif_mass / frame_durations / token_mask.
// Exclusion by range is exact: frames outside have clamp(w)=0 by construction.
// ---------------------------------------------------------------------------
__global__ __launch_bounds__(256) void cif_gather_kernel(
    const float* __restrict__ h, const float* __restrict__ alpha,
    const float* __restrict__ c_arr,
    const int* __restrict__ tgt, const int* __restrict__ ilen,
    float* __restrict__ hw, float* __restrict__ fd_out,
    float* __restrict__ cm_out, float* __restrict__ tm_out)
{
    const int n   = blockIdx.x;
    const int b   = blockIdx.y;
    const int tid = threadIdx.x;
    const int oidx = b * N_MAX + n;
    const int tg   = tgt[b];
    if (n >= tg) {
        if (tid == 0) { fd_out[oidx] = 0.f; cm_out[oidx] = 0.f; tm_out[oidx] = 0.f; }
        return;   // hw row left as (finite) poison; K4 masks it to zero
    }
    const int L = min(ilen[b], T_LEN);
    const float* cb = c_arr + b * T_LEN;
    const float* ab = alpha + b * T_LEN;
    const float nf  = (float)n;
    const float nf1 = nf + 1.0f;

    // first t with c[t] > n
    int lo = 0, hi = T_LEN;
    while (lo < hi) { int mid = (lo + hi) >> 1; if (cb[mid] > nf) hi = mid; else lo = mid + 1; }
    const int t0 = lo;
    // first t with c[t] >= n+1  (== last contributing frame, since c_prev[t]=c[t-1])
    lo = 0; hi = T_LEN;
    while (lo < hi) { int mid = (lo + hi) >> 1; if (cb[mid] >= nf1) hi = mid; else lo = mid + 1; }
    int t1 = min(lo, L - 1);

    float2 acc = make_float2(0.f, 0.f);
    float wsum = 0.f, fdsum = 0.f;
    const float* hb = h + (size_t)(b * T_LEN) * D_DIM;
    for (int t = t0; t <= t1; ++t) {
        float a = ab[t], c = cb[t];
        float cp = c - a;                               // c_prev, same arithmetic as ref
        float w  = fminf(c, nf1) - fmaxf(cp, nf);
        w = fmaxf(w, 0.f);
        wsum  += w;
        fdsum += w / (a + EPSF);
        const float2 hv = *(const float2*)(hb + (size_t)t * D_DIM + tid * 2);
        acc.x += w * hv.x;
        acc.y += w * hv.y;
    }
    *(float2*)(hw + (size_t)oidx * D_DIM + tid * 2) = acc;
    if (tid == 0) { fd_out[oidx] = fdsum; cm_out[oidx] = wsum; tm_out[oidx] = 1.f; }
}

// ---------------------------------------------------------------------------
// K4: tokens = (hw @ Wv + cif_mass*bv) * token_mask.  M=6400, N=512, K=512.
// 32x128 tile per block, 4x4 micro-tile per thread, A staged in LDS.
// ---------------------------------------------------------------------------
__global__ __launch_bounds__(256) void token_gemm_kernel(
    const float* __restrict__ hw, const float* __restrict__ Wv,
    const float* __restrict__ bv, const float* __restrict__ cm,
    const int* __restrict__ tgt, float* __restrict__ tokens)
{
    __shared__ float As[32][516];
    const int tid  = threadIdx.x;
    const int row0 = blockIdx.x * 32;
    const int colb = blockIdx.y * 128;

    const float4* src = (const float4*)(hw + (size_t)row0 * D_DIM);
    #pragma unroll
    for (int i = 0; i < 16; ++i) {
        int idx = tid + i * 256;
        float4 v = src[idx];
        *(float4*)&As[idx >> 7][(idx & 127) << 2] = v;
    }
    __syncthreads();

    const int tc = tid & 31;
    const int tr = tid >> 5;
    const int col = colb + tc * 4;
    const int rbase = tr * 4;
    float acc[4][4] = {};
    for (int k4 = 0; k4 < 128; ++k4) {
        int k = k4 << 2;
        float4 wA = *(const float4*)&Wv[(size_t)(k + 0) * D_DIM + col];
        float4 wB = *(const float4*)&Wv[(size_t)(k + 1) * D_DIM + col];
        float4 wC = *(const float4*)&Wv[(size_t)(k + 2) * D_DIM + col];
        float4 wD = *(const float4*)&Wv[(size_t)(k + 3) * D_DIM + col];
        float4 x0 = *(const float4*)&As[rbase + 0][k];
        float4 x1 = *(const float4*)&As[rbase + 1][k];
        float4 x2 = *(const float4*)&As[rbase + 2][k];
        float4 x3 = *(const float4*)&As[rbase + 3][k];
        FMA16(wA, x0.x, x1.x, x2.x, x3.x);
        FMA16(wB, x0.y, x1.y, x2.y, x3.y);
        FMA16(wC, x0.z, x1.z, x2.z, x3.z);
        FMA16(wD, x0.w, x1.w, x2.w, x3.w);
    }

    float4 bq = *(const float4*)&bv[col];
    #pragma unroll
    for (int r = 0; r < 4; ++r) {
        int row = row0 + rbase + r;
        int bb  = row / N_MAX;
        int nn  = row - bb * N_MAX;
        float m  = (nn < tgt[bb]) ? 1.f : 0.f;
        float wm = cm[row];                     // already masked (0 for masked bins)
        float4 o;
        o.x = m * (acc[r][0] + wm * bq.x);
        o.y = m * (acc[r][1] + wm * bq.y);
        o.z = m * (acc[r][2] + wm * bq.z);
        o.w = m * (acc[r][3] + wm * bq.w);
        *(float4*)&tokens[(size_t)row * D_DIM + col] = o;
    }
}

// ---------------------------------------------------------------------------
extern "C" void kernel_launch(void* const* d_in, const int* in_sizes, int n_in,
                              void* d_out, int out_size, void* d_ws, size_t ws_size,
                              hipStream_t stream)
{
    (void)in_sizes; (void)n_in; (void)out_size; (void)ws_size;
    const float* h    = (const float*)d_in[0];
    const int*   tgt  = (const int*)  d_in[1];
    const int*   ilen = (const int*)  d_in[2];
    const float* lng  = (const float*)d_in[3];
    const float* lnb  = (const float*)d_in[4];
    const float* W1   = (const float*)d_in[5];
    const float* b1   = (const float*)d_in[6];
    const float* W2   = (const float*)d_in[7];
    const float* b2   = (const float*)d_in[8];
    const float* Wv   = (const float*)d_in[9];
    const float* bv   = (const float*)d_in[10];

    float* out    = (float*)d_out;
    float* tokens = out;                                        // [B, N_MAX, V]
    float* fd     = tokens + (size_t)B_SZ * N_MAX * D_DIM;      // [B, N_MAX]
    float* cm     = fd + B_SZ * N_MAX;                          // [B, N_MAX]
    float* tm     = cm + B_SZ * N_MAX;                          // [B, N_MAX]
    float* alpha  = tm + B_SZ * N_MAX;                          // [B, T]
    float* raw    = alpha + B_SZ * T_LEN;                       // [B, T]

    float* c_ws = (float*)d_ws;                                 // [B, T]
    float* hw   = c_ws + (size_t)B_SZ * T_LEN;                  // [B*N_MAX, D]

    alpha_net_kernel<<<(B_SZ * T_LEN) / 32, 256, 0, stream>>>(h, lng, lnb, W1, b1, W2, b2, raw);
    scan_kernel<<<B_SZ, 1024, 0, stream>>>(raw, tgt, ilen, alpha, c_ws);
    cif_gather_kernel<<<dim3(N_MAX, B_SZ), 256, 0, stream>>>(h, alpha, c_ws, tgt, ilen,
                                                             hw, fd, cm, tm);
    token_gemm_kernel<<<dim3((B_SZ * N_MAX) / 32, 4), 256, 0, stream>>>(hw, Wv, bv, cm, tgt, tokens);
}